// Round 10
// baseline (223.792 us; speedup 1.0000x reference)
//
#include <hip/hip_runtime.h>
#include <hip/hip_bf16.h>
#include <math.h>

#define DIM 1024
#define HID 2048
#define NEXP 8
#define NTOK 1024   // B*T
#define TOPK 2

typedef __attribute__((ext_vector_type(4))) float f32x4;
typedef __attribute__((ext_vector_type(8))) short bf16x8;
typedef __attribute__((ext_vector_type(4))) short bf16x4;

__device__ inline short bf1(float f) {
    union { __hip_bfloat16 b; short s; } u; u.b = __float2bfloat16(f); return u.s;
}
__device__ inline bf16x4 cvt4(f32x4 v) {
    bf16x4 r;
#pragma unroll
    for (int i = 0; i < 4; ++i) r[i] = bf1(v[i]);
    return r;
}
__device__ inline bf16x8 cat8(bf16x4 lo, bf16x4 hi) {
    bf16x8 r;
#pragma unroll
    for (int i = 0; i < 4; ++i) { r[i] = lo[i]; r[i + 4] = hi[i]; }
    return r;
}

// async global->LDS: LDS dest = wave-uniform base + lane*16; global src per-lane.
__device__ __forceinline__ void gload16(const void* g, void* l) {
    __builtin_amdgcn_global_load_lds(
        (const __attribute__((address_space(1))) void*)g,
        (__attribute__((address_space(3))) void*)l,
        16, 0, 0);
}

// ---------------- router (fused with x->bf16 convert) ----------------
__global__ __launch_bounds__(64) void router_kernel(
    const float* __restrict__ x, const float* __restrict__ rw,
    __hip_bfloat16* __restrict__ xb,
    int* __restrict__ counts, int* __restrict__ slot_list, float* __restrict__ w_list)
{
    int t = blockIdx.x;
    int lane = threadIdx.x;
    const float* xr = x + (size_t)t * DIM;
    f32x4 xv[4];
#pragma unroll
    for (int qq = 0; qq < 4; ++qq) xv[qq] = *(const f32x4*)(xr + qq * 256 + lane * 4);
#pragma unroll
    for (int qq = 0; qq < 4; ++qq)
        *(bf16x4*)(xb + (size_t)t * DIM + qq * 256 + lane * 4) = cvt4(xv[qq]);

    float acc[NEXP];
#pragma unroll
    for (int e = 0; e < NEXP; ++e) {
        const float* rwe = rw + e * DIM;
        f32x4 s4 = (f32x4)(0.f);
#pragma unroll
        for (int qq = 0; qq < 4; ++qq) {
            f32x4 wv = *(const f32x4*)(rwe + qq * 256 + lane * 4);
            s4 += xv[qq] * wv;
        }
        acc[e] = s4[0] + s4[1] + s4[2] + s4[3];
    }
#pragma unroll
    for (int off = 32; off > 0; off >>= 1) {
#pragma unroll
        for (int e = 0; e < NEXP; ++e) acc[e] += __shfl_down(acc[e], off, 64);
    }
    if (lane == 0) {
        int i1 = 0;
#pragma unroll
        for (int e = 1; e < NEXP; ++e) if (acc[e] > acc[i1]) i1 = e;
        int i2 = -1;
#pragma unroll
        for (int e = 0; e < NEXP; ++e) {
            if (e == i1) continue;
            if (i2 < 0 || acc[e] > acc[i2]) i2 = e;
        }
        float w1 = 1.f / (1.f + expf(acc[i2] - acc[i1]));   // softmax renorm over top-2
        float w2 = 1.f - w1;
        int p1 = atomicAdd(&counts[i1], 1);
        slot_list[i1 * NTOK + p1] = t * 2 + 0;
        w_list[i1 * NTOK + p1] = w1;
        int p2 = atomicAdd(&counts[i2], 1);
        slot_list[i2 * NTOK + p2] = t * 2 + 1;
        w_list[i2 * NTOK + p2] = w2;
    }
}

// ---------------- gate+up: B-strip resident in LDS (full K), contiguous weight stream ----------------
// Block = (expert e, 16-col strip of G AND U). Stage 32 weight rows x 4KB f32
// CONTIGUOUSLY (page-friendly), cvt -> 64KB bf16 B-LDS once; K-loop streams only
// the X tile (L2-resident) via global_load_lds dbuf. Each weight byte fetched
// exactly once chip-wide; all strip-blocks of an expert do identical work.
// Wave wv owns token rows wv*16..+15; per step 4 MFMA (2 kh x {G,U}).
__global__ __launch_bounds__(256) void gateup_mfma(
    const __hip_bfloat16* __restrict__ xb, const float* __restrict__ wg,
    const float* __restrict__ wu, const int* __restrict__ counts,
    const int* __restrict__ slot_list, const float* __restrict__ w_list,
    const __hip_bfloat16* __restrict__ zrow, __hip_bfloat16* __restrict__ h_buf)
{
    __shared__ short Bs[32 * 1024];   // 64KB: rows 0-15 = G strip, 16-31 = U strip; slot-swizzled
    __shared__ short Xs[2][64 * 64];  // 2 x 8KB X tiles (64 tokens x BK=64)

    int bid = blockIdx.x;
    int e = bid >> 7;                 // 8 experts x 128 strips
    int hb = (bid & 127) * 16;

    int n_e = counts[e];
    if (n_e == 0) return;
    const int* sl = slot_list + e * NTOK;
    const float* wl = w_list + e * NTOK;
    const float* WG = wg + (size_t)e * HID * DIM;
    const float* WU = wu + (size_t)e * HID * DIM;

    int tid = threadIdx.x, lane = tid & 63, wv = tid >> 6;
    int fr = lane & 15, fq = lane >> 4;

    // ---- one-time B staging: contiguous f32 rows -> bf16 LDS, slot = c ^ (r&7) ----
#pragma unroll 4
    for (int it = 0; it < 16; ++it) {
        int dc = it * 256 + tid;      // dest 16B chunk 0..4095
        int r = dc >> 7;              // 0..31
        int c = dc & 127;             // 16B chunk within bf16 row (= 32B of src f32)
        const float* srow = (r < 16) ? (WG + (size_t)(hb + r) * DIM)
                                     : (WU + (size_t)(hb + (r - 16)) * DIM);
        f32x4 lo = *(const f32x4*)(srow + c * 8);
        f32x4 hi = *(const f32x4*)(srow + c * 8 + 4);
        *(bf16x8*)&Bs[r * 1024 + ((c ^ (r & 7)) * 8)] = cat8(cvt4(lo), cvt4(hi));
    }
    __syncthreads();

    // X staging lane decode: wave stages rows wv*16..+15 as 2 gloads of 8 rows x 128B
    int rl = lane >> 3;               // local row 0..7
    int soff = ((lane & 7) ^ rl) << 4;   // source chunk swizzle (both-sides rule)
    char* dA = (char*)&Xs[0][0] + wv * 2048;   // buf0 dest for rows wv*16..; +1024 = rows +8

    for (int m0 = 0; m0 < n_e; m0 += 64) {
        int rows = n_e - m0; if (rows > 64) rows = 64;
        int ra = wv * 16 + rl, rb = ra + 8;
        const char* pa = (const char*)((ra < rows) ? (xb + (size_t)(sl[m0 + ra] >> 1) * DIM) : zrow) + soff;
        const char* pb = (const char*)((rb < rows) ? (xb + (size_t)(sl[m0 + rb] >> 1) * DIM) : zrow) + soff;

        f32x4 accg = (f32x4)(0.f), accu = (f32x4)(0.f);

        // prologue: stage steps 0,1
        gload16(pa, dA);              gload16(pb, dA + 1024);
        gload16(pa + 128, dA + 8192); gload16(pb + 128, dA + 8192 + 1024);

#pragma unroll
        for (int t = 0; t < 16; ++t) {
            if (t < 15) asm volatile("s_waitcnt vmcnt(2)" ::: "memory");
            else        asm volatile("s_waitcnt vmcnt(0)" ::: "memory");
            __builtin_amdgcn_s_barrier();
            __builtin_amdgcn_sched_barrier(0);
            const short* Xb = &Xs[t & 1][0];
#pragma unroll
            for (int kh = 0; kh < 2; ++kh) {
                int sa = kh * 4 + fq;                       // chunk within BK
                bf16x8 a  = *(const bf16x8*)&Xb[(wv * 16 + fr) * 64 + ((sa ^ (fr & 7)) * 8)];
                bf16x8 bg = *(const bf16x8*)&Bs[fr * 1024 + (((t * 8 + sa) ^ (fr & 7)) * 8)];
                bf16x8 bu = *(const bf16x8*)&Bs[(16 + fr) * 1024 + (((t * 8 + sa) ^ (fr & 7)) * 8)];
                accg = __builtin_amdgcn_mfma_f32_16x16x32_bf16(a, bg, accg, 0, 0, 0);
                accu = __builtin_amdgcn_mfma_f32_16x16x32_bf16(a, bu, accu, 0, 0, 0);
            }
            __builtin_amdgcn_sched_barrier(0);
            __builtin_amdgcn_s_barrier();
            if (t < 14) {             // stage step t+2 into the just-freed buffer
                char* dd = dA + (t & 1) * 8192;
                gload16(pa + (t + 2) * 128, dd);
                gload16(pb + (t + 2) * 128, dd + 1024);
            }
        }

        // epilogue: h = w * silu(g) * u  (D row = wv*16 + fq*4 + reg, col = fr)
#pragma unroll
        for (int reg = 0; reg < 4; ++reg) {
            int r = wv * 16 + fq * 4 + reg;
            if (r < rows) {
                int slot = sl[m0 + r];
                float w = wl[m0 + r];
                float g = accg[reg], u = accu[reg];
                float h = w * (g / (1.f + expf(-g))) * u;
                h_buf[(size_t)slot * HID + hb + fr] = __float2bfloat16(h);
            }
        }
    }
}

// ---------------- down: same structure; Wd strip (16 d-cols, full K=2048) in LDS ----------------
__global__ __launch_bounds__(256) void down_mfma(
    const __hip_bfloat16* __restrict__ h_buf, const float* __restrict__ wd,
    const int* __restrict__ counts, const int* __restrict__ slot_list,
    const __hip_bfloat16* __restrict__ zrow, float* __restrict__ ybuf)
{
    __shared__ short Bs[16 * 2048];   // 64KB: 16 Wd rows x 2048 bf16, slot-swizzled
    __shared__ short Hs[2][64 * 64];  // 2 x 8KB

    int bid = blockIdx.x;
    int e = bid >> 6;                 // 8 experts x 64 strips
    int db = (bid & 63) * 16;

    int n_e = counts[e];
    if (n_e == 0) return;
    const int* sl = slot_list + e * NTOK;
    const float* WD = wd + (size_t)e * DIM * HID;

    int tid = threadIdx.x, lane = tid & 63, wv = tid >> 6;
    int fr = lane & 15, fq = lane >> 4;

#pragma unroll 4
    for (int it = 0; it < 16; ++it) {
        int dc = it * 256 + tid;      // 0..4095
        int r = dc >> 8;              // 0..15
        int c = dc & 255;
        const float* srow = WD + (size_t)(db + r) * HID;
        f32x4 lo = *(const f32x4*)(srow + c * 8);
        f32x4 hi = *(const f32x4*)(srow + c * 8 + 4);
        *(bf16x8*)&Bs[r * 2048 + ((c ^ (r & 7)) * 8)] = cat8(cvt4(lo), cvt4(hi));
    }
    __syncthreads();

    int rl = lane >> 3;
    int soff = ((lane & 7) ^ rl) << 4;
    char* dA = (char*)&Hs[0][0] + wv * 2048;

    for (int m0 = 0; m0 < n_e; m0 += 64) {
        int rows = n_e - m0; if (rows > 64) rows = 64;
        int ra = wv * 16 + rl, rb = ra + 8;
        const char* pa = (const char*)((ra < rows) ? (h_buf + (size_t)sl[m0 + ra] * HID) : zrow) + soff;
        const char* pb = (const char*)((rb < rows) ? (h_buf + (size_t)sl[m0 + rb] * HID) : zrow) + soff;

        f32x4 acc = (f32x4)(0.f);

        gload16(pa, dA);              gload16(pb, dA + 1024);
        gload16(pa + 128, dA + 8192); gload16(pb + 128, dA + 8192 + 1024);

#pragma unroll
        for (int t = 0; t < 32; ++t) {
            if (t < 31) asm volatile("s_waitcnt vmcnt(2)" ::: "memory");
            else        asm volatile("s_waitcnt vmcnt(0)" ::: "memory");
            __builtin_amdgcn_s_barrier();
            __builtin_amdgcn_sched_barrier(0);
            const short* Hb = &Hs[t & 1][0];
#pragma unroll
            for (int kh = 0; kh < 2; ++kh) {
                int sa = kh * 4 + fq;
                bf16x8 a = *(const bf16x8*)&Hb[(wv * 16 + fr) * 64 + ((sa ^ (fr & 7)) * 8)];
                bf16x8 b = *(const bf16x8*)&Bs[fr * 2048 + (((t * 8 + sa) ^ (fr & 7)) * 8)];
                acc = __builtin_amdgcn_mfma_f32_16x16x32_bf16(a, b, acc, 0, 0, 0);
            }
            __builtin_amdgcn_sched_barrier(0);
            __builtin_amdgcn_s_barrier();
            if (t < 30) {
                char* dd = dA + (t & 1) * 8192;
                gload16(pa + (t + 2) * 128, dd);
                gload16(pb + (t + 2) * 128, dd + 1024);
            }
        }

#pragma unroll
        for (int reg = 0; reg < 4; ++reg) {
            int r = wv * 16 + fq * 4 + reg;
            if (r < rows) {
                int slot = sl[m0 + r];
                ybuf[(size_t)slot * DIM + db + fr] = acc[reg];
            }
        }
    }
}

// ---------------- combine: out[t] = y[2t] + y[2t+1] ----------------
__global__ __launch_bounds__(256) void combine_kernel(const float* __restrict__ ybuf, float* __restrict__ out)
{
    int i = blockIdx.x * 256 + threadIdx.x;
    int t = i >> 8;
    int c = i & 255;
    const float4* ya = (const float4*)(ybuf + (size_t)(2 * t) * DIM) + c;
    const float4* yb = (const float4*)(ybuf + (size_t)(2 * t + 1) * DIM) + c;
    float4 a = *ya, b = *yb, r;
    r.x = a.x + b.x; r.y = a.y + b.y; r.z = a.z + b.z; r.w = a.w + b.w;
    ((float4*)(out + (size_t)t * DIM))[c] = r;
}

extern "C" void kernel_launch(void* const* d_in, const int* in_sizes, int n_in,
                              void* d_out, int out_size, void* d_ws, size_t ws_size,
                              hipStream_t stream) {
    const float* x  = (const float*)d_in[0];
    const float* rw = (const float*)d_in[1];
    const float* wg = (const float*)d_in[2];
    const float* wu = (const float*)d_in[3];
    const float* wd = (const float*)d_in[4];
    float* out = (float*)d_out;

    char* ws = (char*)d_ws;
    int* counts            = (int*)ws;                                   // 256 B
    int* slot_list         = (int*)(ws + 256);                           // 32 KB
    float* w_list          = (float*)(ws + 256 + NEXP * NTOK * 4);       // 32 KB
    __hip_bfloat16* xb     = (__hip_bfloat16*)(ws + 256 + 2 * NEXP * NTOK * 4);       // 2 MB
    __hip_bfloat16* h_buf  = (__hip_bfloat16*)((char*)xb + (size_t)NTOK * DIM * 2);   // 8 MB
    float* ybuf            = (float*)((char*)h_buf + (size_t)NTOK * TOPK * HID * 2);  // 8 MB
    __hip_bfloat16* zrow   = (__hip_bfloat16*)((char*)ybuf + (size_t)NTOK * TOPK * DIM * 4); // 4 KB zeros

    hipMemsetAsync(counts, 0, NEXP * sizeof(int), stream);
    hipMemsetAsync(zrow, 0, HID * sizeof(__hip_bfloat16), stream);
    router_kernel<<<NTOK, 64, 0, stream>>>(x, rw, xb, counts, slot_list, w_list);
    gateup_mfma<<<1024, 256, 0, stream>>>(xb, wg, wu, counts, slot_list, w_list, zrow, h_buf);
    down_mfma<<<512, 256, 0, stream>>>(h_buf, wd, counts, slot_list, zrow, ybuf);
    combine_kernel<<<NTOK * DIM / 4 / 256, 256, 0, stream>>>(ybuf, out);
}